// Round 10
// baseline (224.138 us; speedup 1.0000x reference)
//
#include <hip/hip_runtime.h>
#include <hip/hip_bf16.h>
#include <stdint.h>

// out[b,l,i,o] = sum_d head[b,i,d]*U[l,d]*dep[b,o,d] + t2h[b,l,i] + t2d[b,l,o] + b[l]
// B=16, S=256, D=768, L=32. out (16,32,256,256) fp32.
//
// R12: R11 structure (grid 1024, 256 thr, K64 = two phase-local k32 phases,
// 12 lgkm-only barriers, swizzled A-LDS, B direct-to-register ping-pong) with
// wave grid switched 1x4 -> 2x2: wave tile 64(i) x 128(o). Each wave now
// reads only its 64-row A half from LDS (16KB reads + 8KB writes per
// block-iter vs 40KB) -- attacks the estimated ~83%-busy LDS pipe. B-frag
// loads double per wave but waves {0,2}/{1,3} hit identical L1 lines.
// Accumulation order per output element unchanged -> absmax 0.03125.
// prep unchanged from R6.

#define B_ 16
#define S_ 256
#define D_ 768
#define L_ 32
#define KQ_ (D_ / 8)  // 96 groups of 8 d's
#define NT_ 12        // barrier-iters of 64 k
#define NC_ 24        // 32-k chunks total

typedef unsigned short ushort_t;
typedef __attribute__((ext_vector_type(4))) float f32x4;
typedef __attribute__((ext_vector_type(8))) short s16x8;

// round-half-up fp32->bf16 pair pack; f0 -> low half, f1 -> high half
__device__ __forceinline__ unsigned int pack_bf16(float f0, float f1) {
  unsigned int u0 = __builtin_bit_cast(unsigned int, f0) + 0x8000u;
  unsigned int u1 = __builtin_bit_cast(unsigned int, f1) + 0x8000u;
  return __builtin_amdgcn_perm(u1, u0, 0x07060302);
}

// ---------------------------------------------------------------------------
// Prep: one wave per 4 rows. Lane owns 12 d's in registers. t2 dots: per-lane
// FMA partials for 16 labels x 4 rows, then ONE packed transpose-butterfly
// (63 shuffles) delivers output j = l*4 + r to lane j. Two label-chunks.
// dep waves also emit bf16 depb in fragment-major layout
// depb[b][d>>3][col][d&7]. grid = 512 x 256 = 2048 waves = B*S*2/4 rows.
// ---------------------------------------------------------------------------
__global__ __launch_bounds__(256) void prep_kernel(
    const float* __restrict__ head, const float* __restrict__ dep,
    const float* __restrict__ labelW, ushort_t* __restrict__ depb,
    float* __restrict__ t2h, float* __restrict__ t2d) {
  const int wave = threadIdx.x >> 6;
  const int lane = threadIdx.x & 63;
  const int g = blockIdx.x * 4 + wave;  // 0..2047
  const int sel = g >> 10;              // 0=head, 1=dep
  const int idx = g & 1023;
  const int b = idx >> 6;
  const int row0 = (idx & 63) * 4;
  const float* src = sel ? dep : head;
  float* t2x = sel ? t2d : t2h;
  const int d0 = lane * 12;

  float h[4][12];
  const float* rp = src + ((size_t)(b * S_ + row0)) * D_ + d0;
#pragma unroll
  for (int r = 0; r < 4; ++r) {
    float4 v0 = *(const float4*)(rp + (size_t)r * D_);
    float4 v1 = *(const float4*)(rp + (size_t)r * D_ + 4);
    float4 v2 = *(const float4*)(rp + (size_t)r * D_ + 8);
    h[r][0] = v0.x; h[r][1] = v0.y; h[r][2] = v0.z; h[r][3] = v0.w;
    h[r][4] = v1.x; h[r][5] = v1.y; h[r][6] = v1.z; h[r][7] = v1.w;
    h[r][8] = v2.x; h[r][9] = v2.y; h[r][10] = v2.z; h[r][11] = v2.w;
  }
  if (sel) {
    // fragment-major: ushort off = ((b*96 + (d>>3))*256 + col)*8 + (d&7)
    const size_t bb = (size_t)b * (KQ_ * S_ * 8);
    const int m = lane >> 1;  // d0 = 24m (even lane) or 24m+12 (odd lane)
#pragma unroll
    for (int r = 0; r < 4; ++r) {
      const int col = row0 + r;
      unsigned int q0 = pack_bf16(h[r][0], h[r][1]);
      unsigned int q1 = pack_bf16(h[r][2], h[r][3]);
      unsigned int q2 = pack_bf16(h[r][4], h[r][5]);
      unsigned int q3 = pack_bf16(h[r][6], h[r][7]);
      unsigned int q4 = pack_bf16(h[r][8], h[r][9]);
      unsigned int q5 = pack_bf16(h[r][10], h[r][11]);
      if ((lane & 1) == 0) {
        uint4 a = {q0, q1, q2, q3};  // d0..d7 @ kq=3m
        uint2 c = {q4, q5};          // d8..d11 @ kq=3m+1, dlow 0..3
        *(uint4*)(depb + bb + ((size_t)(3 * m) * S_ + col) * 8) = a;
        *(uint2*)(depb + bb + ((size_t)(3 * m + 1) * S_ + col) * 8) = c;
      } else {
        uint2 c = {q0, q1};          // d0..d3 @ kq=3m+1, dlow 4..7
        uint4 a = {q2, q3, q4, q5};  // d4..d11 @ kq=3m+2
        *(uint2*)(depb + bb + ((size_t)(3 * m + 1) * S_ + col) * 8 + 4) = c;
        *(uint4*)(depb + bb + ((size_t)(3 * m + 2) * S_ + col) * 8) = a;
      }
    }
  }
  const float* wbase = labelW + sel * D_ + d0;
  // two chunks of 16 labels; v[j] = partial for output j = lq*4 + r
  for (int c = 0; c < 2; ++c) {
    float v[64];
#pragma unroll
    for (int j = 0; j < 64; ++j) v[j] = 0.f;
    const float* wc = wbase + (size_t)(c * 16) * (2 * D_);
#pragma unroll
    for (int lq = 0; lq < 16; ++lq) {
      const float* wp = wc + (size_t)lq * (2 * D_);
      float4 w0 = *(const float4*)(wp);
      float4 w1 = *(const float4*)(wp + 4);
      float4 w2 = *(const float4*)(wp + 8);
      float w[12] = {w0.x, w0.y, w0.z, w0.w, w1.x, w1.y, w1.z, w1.w,
                     w2.x, w2.y, w2.z, w2.w};
#pragma unroll
      for (int j = 0; j < 12; ++j) {
        v[lq * 4 + 0] += h[0][j] * w[j];
        v[lq * 4 + 1] += h[1][j] * w[j];
        v[lq * 4 + 2] += h[2][j] * w[j];
        v[lq * 4 + 3] += h[3][j] * w[j];
      }
    }
    // packed transpose-butterfly: combine order (own + partner, high bit
    // first) matches the old per-output allreduce bit-for-bit.
#pragma unroll
    for (int off = 32; off >= 1; off >>= 1) {
      const bool hi = (lane & off) != 0;
#pragma unroll
      for (int k = 0; k < 64; ++k) {
        if (k >= off) continue;  // live window is [0, off)
        float send = hi ? v[k] : v[k + off];
        float keep = hi ? v[k + off] : v[k];
        v[k] = keep + __shfl_xor(send, off);
      }
    }
    t2x[((size_t)(b * L_ + c * 16 + (lane >> 2))) * S_ + row0 + (lane & 3)] =
        v[0];
  }
}

// ---------------------------------------------------------------------------
// Main: block = (b, l, i-half). Tile 128(i) x 256(o), 4 waves of 64x128
// (2 row-halves x 2 col-halves). grid = B*L*2 = 1024 blocks, 256 threads.
// ---------------------------------------------------------------------------

// XOR-swizzle on ushort offsets within a 4KB phase sub-buffer: kgrp (bits
// 11:10) into bits 5:4. Bijective; both A ds_write and ds_read uniform 2/bank.
#define SWZ(o) ((o) ^ ((((o) >> 10) & 3) << 4))

__global__ __launch_bounds__(256, 2) void main_kernel(
    const float* __restrict__ head, const ushort_t* __restrict__ depb,
    const float* __restrict__ U, const float* __restrict__ bias,
    const float* __restrict__ t2h, const float* __restrict__ t2d,
    float* __restrict__ out) {
  // A: [buf(2)][phase(2)][kgrp(4)][row(128)][8] bf16, XOR-swizzled per phase
  __shared__ __attribute__((aligned(16))) ushort_t As[2 * 2 * 4096];  // 32 KB
  __shared__ float T2[384];  // [0:128]=t2h tile rows, [128:384]=t2d all cols

  // XCD-bijective swizzle: grid 1024 = 8 XCDs x 128 contiguous blocks (2 b's)
  const int hw = blockIdx.x;
  const int bid = ((hw & 7) << 7) | (hw >> 3);
  const int ic = bid & 1;
  const int bl = bid >> 1;
  const int l = bl & (L_ - 1);
  const int b = bl >> 5;
  const int ti = ic * 128;
  const int t = threadIdx.x;
  const int lane = t & 63;
  const int wave = t >> 6;
  const int wr = wave >> 1;  // row half: rows wr*64..+64
  const int wc = wave & 1;   // col half: cols wc*128..+128

  for (int i = t; i < 384; i += 256)
    T2[i] = (i < 128) ? t2h[((size_t)(b * L_ + l)) * S_ + ti + i]
                      : t2d[((size_t)(b * L_ + l)) * S_ + (i - 128)];
  const float bv = bias[l];

  // A staging decomposition: thread t stages rows (t>>2, t>>2+64), kgrp t&3
  const int row0 = t >> 2;
  const int kg = t & 3;
  const float* hp0 = head + ((size_t)(b * S_ + ti + row0)) * D_ + kg * 8;
  const float* hp1 = hp0 + (size_t)64 * D_;
  const float* Up = U + (size_t)l * D_ + kg * 8;
  const int awo0s = SWZ((kg * 128 + row0) * 8);
  const int awo1s = awo0s + 512;  // +64 rows; doesn't touch swizzled bits

  // A frag reads: rows wr*64 + rt*16 + (lane&15), kgrp=lane>>4.
  // wr*512 and rt*128 (rt<4) stay below bit 10 and above bit 5 -> safe to
  // add post-swizzle (no aliasing with SWZ source/target bits).
  const int aros = SWZ(((lane >> 4) * 128 + (lane & 15)) * 8) + wr * 512;

  // B direct-from-global: wave owns cols [wc*128, wc*128+128)
  const ushort_t* dfb =
      depb + (size_t)b * (KQ_ * S_ * 8) +
      ((size_t)((lane >> 4) * 256 + wc * 128 + (lane & 15))) * 8;

  f32x4 acc[4][8];
#pragma unroll
  for (int i = 0; i < 4; ++i)
#pragma unroll
    for (int j = 0; j < 8; ++j) acc[i][j] = {0.f, 0.f, 0.f, 0.f};

  s16x8 bfA[8], bfB[8];

#define LOAD_HU(ku)                                                           \
    float4 h0 = *(const float4*)(hp0 + (ku) * 32);                            \
    float4 h1 = *(const float4*)(hp0 + (ku) * 32 + 4);                        \
    float4 h2 = *(const float4*)(hp1 + (ku) * 32);                            \
    float4 h3 = *(const float4*)(hp1 + (ku) * 32 + 4);                        \
    float4 u0 = *(const float4*)(Up + (ku) * 32);                             \
    float4 u1 = *(const float4*)(Up + (ku) * 32 + 4);

#define PACK_WRITE_A(DST)                                                     \
  {                                                                           \
    uint4 w0, w1;                                                             \
    w0.x = pack_bf16(h0.x * u0.x, h0.y * u0.y);                               \
    w0.y = pack_bf16(h0.z * u0.z, h0.w * u0.w);                               \
    w0.z = pack_bf16(h1.x * u1.x, h1.y * u1.y);                               \
    w0.w = pack_bf16(h1.z * u1.z, h1.w * u1.w);                               \
    w1.x = pack_bf16(h2.x * u0.x, h2.y * u0.y);                               \
    w1.y = pack_bf16(h2.z * u0.z, h2.w * u0.w);                               \
    w1.z = pack_bf16(h3.x * u1.x, h3.y * u1.y);                               \
    w1.w = pack_bf16(h3.z * u1.z, h3.w * u1.w);                               \
    *(uint4*)((DST) + awo0s) = w0;                                            \
    *(uint4*)((DST) + awo1s) = w1;                                            \
  }

#define LOAD_BF(DSTB, chunk)                                                  \
  {                                                                           \
    const ushort_t* dfn = dfb + (size_t)(chunk) * 8192;                       \
    _Pragma("unroll") for (int ct = 0; ct < 8; ++ct)                          \
        DSTB[ct] = *(const s16x8*)(dfn + ct * 128);                           \
  }

#define MFMA16(AFB, BFB)                                                      \
  {                                                                           \
    _Pragma("unroll") for (int rt = 0; rt < 4; ++rt)                          \
      _Pragma("unroll") for (int ct = 0; ct < 8; ++ct)                        \
          acc[rt][ct] = __builtin_amdgcn_mfma_f32_16x16x32_bf16(              \
              AFB[rt], BFB[ct], acc[rt][ct], 0, 0, 0);                        \
  }

  // prologue: stage chunks 0,1 into As[0][0..1]; load bfA <- B chunk 0
  {
    {
      LOAD_HU(0)
      PACK_WRITE_A(As)
    }
    {
      LOAD_HU(1)
      PACK_WRITE_A(As + 4096)
    }
    LOAD_BF(bfA, 0)
  }
  asm volatile("s_waitcnt lgkmcnt(0)" ::: "memory");
  __builtin_amdgcn_s_barrier();
  __builtin_amdgcn_sched_barrier(0);

  // Barrier-iter tt (chunks 2tt, 2tt+1 from As[cur]): phase 0 consumes bfA +
  // As[cur][0], prefetches B 2tt+1 -> bfB and stages 2tt+2 -> As[cur^1][0];
  // phase 1 consumes bfB + As[cur][1], prefetches B 2tt+2 -> bfA and stages
  // 2tt+3 -> As[cur^1][1]. One lgkm drain + barrier per iter (12 total).
  int cur = 0;
  for (int tt = 0; tt < NT_; ++tt) {
    const ushort_t* pr = As + cur * 8192;         // read buffer
    ushort_t* pw = As + (cur ^ 1) * 8192;         // write buffer
    // ---- phase 0 ----
    {
      LOAD_BF(bfB, 2 * tt + 1)
      int ks = 2 * tt + 2;                        // staging chunk
      if (ks >= NC_) ks -= NC_;                   // wrapped dummy on last iter
      LOAD_HU(ks)
      __builtin_amdgcn_sched_barrier(0);          // pin load-issue cluster
      s16x8 af[4];
#pragma unroll
      for (int rt = 0; rt < 4; ++rt)
        af[rt] = *(const s16x8*)(pr + aros + rt * 128);
      __builtin_amdgcn_s_setprio(1);
      MFMA16(af, bfA)
      __builtin_amdgcn_s_setprio(0);
      PACK_WRITE_A(pw)
    }
    // ---- phase 1 ----
    {
      int cb = 2 * tt + 2;                        // B chunk for next iter
      if (cb >= NC_) cb -= NC_;                   // wrapped dummy on last iter
      LOAD_BF(bfA, cb)
      int ks = 2 * tt + 3;                        // staging chunk
      if (ks >= NC_) ks -= NC_;
      LOAD_HU(ks)
      __builtin_amdgcn_sched_barrier(0);          // pin load-issue cluster
      s16x8 af[4];
#pragma unroll
      for (int rt = 0; rt < 4; ++rt)
        af[rt] = *(const s16x8*)(pr + 4096 + aros + rt * 128);
      __builtin_amdgcn_s_setprio(1);
      MFMA16(af, bfB)
      __builtin_amdgcn_s_setprio(0);
      PACK_WRITE_A(pw + 4096)
    }
    asm volatile("s_waitcnt lgkmcnt(0)" ::: "memory");
    __builtin_amdgcn_s_barrier();
    __builtin_amdgcn_sched_barrier(0);
    cur ^= 1;
  }
#undef LOAD_HU
#undef PACK_WRITE_A
#undef LOAD_BF
#undef MFMA16

  // epilogue: C/D layout col=lane&15, row=(lane>>4)*4+reg
  const int colg = lane & 15;
  const int rgrp = lane >> 4;
  float* ob = out + (((size_t)(b * L_ + l)) * S_ + ti + wr * 64) * S_ + wc * 128;
#pragma unroll
  for (int rt = 0; rt < 4; ++rt) {
    const int r0 = rt * 16 + rgrp * 4;
#pragma unroll
    for (int ct = 0; ct < 8; ++ct) {
      const int c = ct * 16 + colg;
      const float addc = T2[128 + wc * 128 + c] + bv;
      float* p = ob + (size_t)r0 * S_ + c;
#pragma unroll
      for (int r = 0; r < 4; ++r)
        p[(size_t)r * S_] = acc[rt][ct][r] + T2[wr * 64 + r0 + r] + addc;
    }
  }
}

extern "C" void kernel_launch(void* const* d_in, const int* in_sizes, int n_in,
                              void* d_out, int out_size, void* d_ws, size_t ws_size,
                              hipStream_t stream) {
  const float* head = (const float*)d_in[0];
  const float* dep = (const float*)d_in[1];
  const float* U = (const float*)d_in[2];
  const float* W = (const float*)d_in[3];
  const float* bias = (const float*)d_in[4];
  float* out = (float*)d_out;

  ushort_t* depb = (ushort_t*)d_ws;                              // 6,291,456 B
  float* t2h = (float*)((char*)d_ws + (size_t)B_ * S_ * D_ * 2);
  float* t2d = t2h + (size_t)B_ * L_ * S_;                       // 524,288 B each

  prep_kernel<<<512, 256, 0, stream>>>(head, dep, W, depb, t2h, t2d);
  main_kernel<<<B_ * L_ * 2, 256, 0, stream>>>(head, depb, U, bias, t2h, t2d, out);
}

// Round 11
// 219.628 us; speedup vs baseline: 1.0205x; 1.0205x over previous
//
#include <hip/hip_runtime.h>
#include <hip/hip_bf16.h>
#include <stdint.h>

// out[b,l,i,o] = sum_d head[b,i,d]*U[l,d]*dep[b,o,d] + t2h[b,l,i] + t2d[b,l,o] + b[l]
// B=16, S=256, D=768, L=32. out (16,32,256,256) fp32.
//
// R13: R12's LDS-traffic reduction (2x2 wave grid, wave tile 64x128: block
// LDS = 24KB/iter vs R5's 40KB) with the spill engineered out: B operand in
// 48 regs via split-lead (bfLo ping-pong one iter ahead, bfHi single set
// reloaded in place post-MFMA, sched_barrier-pinned). Single-phase K32 loop,
// 24 lgkm-only barriers (24 vs 12 proven neutral). Swizzled A-LDS, grid 1024,
// accumulation order per output element unchanged -> absmax 0.03125.
// prep unchanged from R6.

#define B_ 16
#define S_ 256
#define D_ 768
#define L_ 32
#define KQ_ (D_ / 8)  // 96 groups of 8 d's
#define NC_ 24        // 32-k chunks

typedef unsigned short ushort_t;
typedef __attribute__((ext_vector_type(4))) float f32x4;
typedef __attribute__((ext_vector_type(8))) short s16x8;

// round-half-up fp32->bf16 pair pack; f0 -> low half, f1 -> high half
__device__ __forceinline__ unsigned int pack_bf16(float f0, float f1) {
  unsigned int u0 = __builtin_bit_cast(unsigned int, f0) + 0x8000u;
  unsigned int u1 = __builtin_bit_cast(unsigned int, f1) + 0x8000u;
  return __builtin_amdgcn_perm(u1, u0, 0x07060302);
}

// ---------------------------------------------------------------------------
// Prep: one wave per 4 rows. Lane owns 12 d's in registers. t2 dots: per-lane
// FMA partials for 16 labels x 4 rows, then ONE packed transpose-butterfly
// (63 shuffles) delivers output j = l*4 + r to lane j. Two label-chunks.
// dep waves also emit bf16 depb in fragment-major layout
// depb[b][d>>3][col][d&7]. grid = 512 x 256 = 2048 waves = B*S*2/4 rows.
// ---------------------------------------------------------------------------
__global__ __launch_bounds__(256) void prep_kernel(
    const float* __restrict__ head, const float* __restrict__ dep,
    const float* __restrict__ labelW, ushort_t* __restrict__ depb,
    float* __restrict__ t2h, float* __restrict__ t2d) {
  const int wave = threadIdx.x >> 6;
  const int lane = threadIdx.x & 63;
  const int g = blockIdx.x * 4 + wave;  // 0..2047
  const int sel = g >> 10;              // 0=head, 1=dep
  const int idx = g & 1023;
  const int b = idx >> 6;
  const int row0 = (idx & 63) * 4;
  const float* src = sel ? dep : head;
  float* t2x = sel ? t2d : t2h;
  const int d0 = lane * 12;

  float h[4][12];
  const float* rp = src + ((size_t)(b * S_ + row0)) * D_ + d0;
#pragma unroll
  for (int r = 0; r < 4; ++r) {
    float4 v0 = *(const float4*)(rp + (size_t)r * D_);
    float4 v1 = *(const float4*)(rp + (size_t)r * D_ + 4);
    float4 v2 = *(const float4*)(rp + (size_t)r * D_ + 8);
    h[r][0] = v0.x; h[r][1] = v0.y; h[r][2] = v0.z; h[r][3] = v0.w;
    h[r][4] = v1.x; h[r][5] = v1.y; h[r][6] = v1.z; h[r][7] = v1.w;
    h[r][8] = v2.x; h[r][9] = v2.y; h[r][10] = v2.z; h[r][11] = v2.w;
  }
  if (sel) {
    // fragment-major: ushort off = ((b*96 + (d>>3))*256 + col)*8 + (d&7)
    const size_t bb = (size_t)b * (KQ_ * S_ * 8);
    const int m = lane >> 1;  // d0 = 24m (even lane) or 24m+12 (odd lane)
#pragma unroll
    for (int r = 0; r < 4; ++r) {
      const int col = row0 + r;
      unsigned int q0 = pack_bf16(h[r][0], h[r][1]);
      unsigned int q1 = pack_bf16(h[r][2], h[r][3]);
      unsigned int q2 = pack_bf16(h[r][4], h[r][5]);
      unsigned int q3 = pack_bf16(h[r][6], h[r][7]);
      unsigned int q4 = pack_bf16(h[r][8], h[r][9]);
      unsigned int q5 = pack_bf16(h[r][10], h[r][11]);
      if ((lane & 1) == 0) {
        uint4 a = {q0, q1, q2, q3};  // d0..d7 @ kq=3m
        uint2 c = {q4, q5};          // d8..d11 @ kq=3m+1, dlow 0..3
        *(uint4*)(depb + bb + ((size_t)(3 * m) * S_ + col) * 8) = a;
        *(uint2*)(depb + bb + ((size_t)(3 * m + 1) * S_ + col) * 8) = c;
      } else {
        uint2 c = {q0, q1};          // d0..d3 @ kq=3m+1, dlow 4..7
        uint4 a = {q2, q3, q4, q5};  // d4..d11 @ kq=3m+2
        *(uint2*)(depb + bb + ((size_t)(3 * m + 1) * S_ + col) * 8 + 4) = c;
        *(uint4*)(depb + bb + ((size_t)(3 * m + 2) * S_ + col) * 8) = a;
      }
    }
  }
  const float* wbase = labelW + sel * D_ + d0;
  // two chunks of 16 labels; v[j] = partial for output j = lq*4 + r
  for (int c = 0; c < 2; ++c) {
    float v[64];
#pragma unroll
    for (int j = 0; j < 64; ++j) v[j] = 0.f;
    const float* wc = wbase + (size_t)(c * 16) * (2 * D_);
#pragma unroll
    for (int lq = 0; lq < 16; ++lq) {
      const float* wp = wc + (size_t)lq * (2 * D_);
      float4 w0 = *(const float4*)(wp);
      float4 w1 = *(const float4*)(wp + 4);
      float4 w2 = *(const float4*)(wp + 8);
      float w[12] = {w0.x, w0.y, w0.z, w0.w, w1.x, w1.y, w1.z, w1.w,
                     w2.x, w2.y, w2.z, w2.w};
#pragma unroll
      for (int j = 0; j < 12; ++j) {
        v[lq * 4 + 0] += h[0][j] * w[j];
        v[lq * 4 + 1] += h[1][j] * w[j];
        v[lq * 4 + 2] += h[2][j] * w[j];
        v[lq * 4 + 3] += h[3][j] * w[j];
      }
    }
    // packed transpose-butterfly: combine order (own + partner, high bit
    // first) matches the old per-output allreduce bit-for-bit.
#pragma unroll
    for (int off = 32; off >= 1; off >>= 1) {
      const bool hi = (lane & off) != 0;
#pragma unroll
      for (int k = 0; k < 64; ++k) {
        if (k >= off) continue;  // live window is [0, off)
        float send = hi ? v[k] : v[k + off];
        float keep = hi ? v[k + off] : v[k];
        v[k] = keep + __shfl_xor(send, off);
      }
    }
    t2x[((size_t)(b * L_ + c * 16 + (lane >> 2))) * S_ + row0 + (lane & 3)] =
        v[0];
  }
}

// ---------------------------------------------------------------------------
// Main: block = (b, l, i-half). Tile 128(i) x 256(o), 4 waves of 64x128
// (2 row-halves x 2 col-halves). grid = B*L*2 = 1024 blocks, 256 threads.
// ---------------------------------------------------------------------------

// XOR-swizzle on ushort offsets within an 8KB A buffer: kgrp (bits 11:10)
// into bits 5:4. Bijective; both A ds_write and ds_read uniform 2/bank
// (measured 0 conflicts in R12).
#define SWZ(o) ((o) ^ ((((o) >> 10) & 3) << 4))

__global__ __launch_bounds__(256, 2) void main_kernel(
    const float* __restrict__ head, const ushort_t* __restrict__ depb,
    const float* __restrict__ U, const float* __restrict__ bias,
    const float* __restrict__ t2h, const float* __restrict__ t2d,
    float* __restrict__ out) {
  // A: [buf(2)][kgrp(4)][row(128)][8] bf16, XOR-swizzled
  __shared__ __attribute__((aligned(16))) ushort_t As[2 * 4096];  // 16 KB
  __shared__ float T2[384];  // [0:128]=t2h tile rows, [128:384]=t2d all cols

  // XCD-bijective swizzle: grid 1024 = 8 XCDs x 128 contiguous blocks (2 b's)
  const int hw = blockIdx.x;
  const int bid = ((hw & 7) << 7) | (hw >> 3);
  const int ic = bid & 1;
  const int bl = bid >> 1;
  const int l = bl & (L_ - 1);
  const int b = bl >> 5;
  const int ti = ic * 128;
  const int t = threadIdx.x;
  const int lane = t & 63;
  const int wave = t >> 6;
  const int wr = wave >> 1;  // row half: rows wr*64..+64
  const int wc = wave & 1;   // col half: cols wc*128..+128

  for (int i = t; i < 384; i += 256)
    T2[i] = (i < 128) ? t2h[((size_t)(b * L_ + l)) * S_ + ti + i]
                      : t2d[((size_t)(b * L_ + l)) * S_ + (i - 128)];
  const float bv = bias[l];

  // A staging decomposition: thread t stages rows (t>>2, t>>2+64), kgrp t&3
  // (16 consecutive cache lines per wave-load -> transaction-optimal)
  const int row0 = t >> 2;
  const int kg = t & 3;
  const float* hp0 = head + ((size_t)(b * S_ + ti + row0)) * D_ + kg * 8;
  const float* hp1 = hp0 + (size_t)64 * D_;
  const float* Up = U + (size_t)l * D_ + kg * 8;
  const int awo0s = SWZ((kg * 128 + row0) * 8);
  const int awo1s = awo0s + 512;  // +64 rows; doesn't touch swizzled bits

  // A frag reads: rows wr*64 + rt*16 + (lane&15), kgrp=lane>>4.
  // wr*512 (bit 9) and rt*128 (bits 7-8) don't alias SWZ bits -> add post-SWZ.
  const int aros = SWZ(((lane >> 4) * 128 + (lane & 15)) * 8) + wr * 512;

  // B direct-from-global: wave owns cols [wc*128, wc*128+128)
  const ushort_t* dfb =
      depb + (size_t)b * (KQ_ * S_ * 8) +
      ((size_t)((lane >> 4) * 256 + wc * 128 + (lane & 15))) * 8;

  f32x4 acc[4][8];
#pragma unroll
  for (int i = 0; i < 4; ++i)
#pragma unroll
    for (int j = 0; j < 8; ++j) acc[i][j] = {0.f, 0.f, 0.f, 0.f};

  s16x8 bfA[4], bfB[4];  // bfLo ping-pong (ct 0..3 of a chunk)
  s16x8 bfHi[4];         // ct 4..7, single set, reloaded in place

#define LOAD_HU(ku)                                                           \
    float4 h0 = *(const float4*)(hp0 + (ku) * 32);                            \
    float4 h1 = *(const float4*)(hp0 + (ku) * 32 + 4);                        \
    float4 h2 = *(const float4*)(hp1 + (ku) * 32);                            \
    float4 h3 = *(const float4*)(hp1 + (ku) * 32 + 4);                        \
    float4 u0 = *(const float4*)(Up + (ku) * 32);                             \
    float4 u1 = *(const float4*)(Up + (ku) * 32 + 4);

#define PACK_WRITE_A(DST)                                                     \
  {                                                                           \
    uint4 w0, w1;                                                             \
    w0.x = pack_bf16(h0.x * u0.x, h0.y * u0.y);                               \
    w0.y = pack_bf16(h0.z * u0.z, h0.w * u0.w);                               \
    w0.z = pack_bf16(h1.x * u1.x, h1.y * u1.y);                               \
    w0.w = pack_bf16(h1.z * u1.z, h1.w * u1.w);                               \
    w1.x = pack_bf16(h2.x * u0.x, h2.y * u0.y);                               \
    w1.y = pack_bf16(h2.z * u0.z, h2.w * u0.w);                               \
    w1.z = pack_bf16(h3.x * u1.x, h3.y * u1.y);                               \
    w1.w = pack_bf16(h3.z * u1.z, h3.w * u1.w);                               \
    *(uint4*)((DST) + awo0s) = w0;                                            \
    *(uint4*)((DST) + awo1s) = w1;                                            \
  }

#define LOAD_BF4(DSTB, chunk, off)                                            \
  {                                                                           \
    const ushort_t* dfn = dfb + (size_t)(chunk) * 8192;                       \
    _Pragma("unroll") for (int ct = 0; ct < 4; ++ct)                          \
        DSTB[ct] = *(const s16x8*)(dfn + ((off) + ct) * 128);                 \
  }

#define MFMA8(AFB, BFB, CO)                                                   \
  {                                                                           \
    _Pragma("unroll") for (int rt = 0; rt < 4; ++rt)                          \
      _Pragma("unroll") for (int ct = 0; ct < 4; ++ct)                        \
          acc[rt][(CO) + ct] = __builtin_amdgcn_mfma_f32_16x16x32_bf16(       \
              AFB[rt], BFB[ct], acc[rt][(CO) + ct], 0, 0, 0);                 \
  }

  // prologue: stage chunk 0 into buf 0; load bfA (lo) + bfHi (hi) of chunk 0
  {
    LOAD_HU(0)
    PACK_WRITE_A(As)
    LOAD_BF4(bfA, 0, 0)
    LOAD_BF4(bfHi, 0, 4)
  }
  asm volatile("s_waitcnt lgkmcnt(0)" ::: "memory");
  __builtin_amdgcn_s_barrier();
  __builtin_amdgcn_sched_barrier(0);

  // Iter (chunk tcur, A in buf PB): issue next chunk's lo-B (-> BLN) and h/u
  // (full-iter lead, counted vmcnt, in flight across the barrier); 4 af
  // ds_reads; 32 MFMA (lo with BLC, hi with bfHi); reload bfHi in place for
  // chunk tcur+1 (pinned below the MFMAs -> 48-reg B peak, no spill);
  // pack+ds_write chunk tcur+1 into buf PB^1; lgkm-only barrier.
#define ITER(PB, BLC, BLN, tcur)                                              \
  {                                                                           \
    int tn = (tcur) + 1;                                                      \
    if (tn == NC_) tn = 0; /* wrapped dummy prefetch keeps code uniform */    \
    LOAD_BF4(BLN, tn, 0)                                                      \
    LOAD_HU(tn)                                                               \
    __builtin_amdgcn_sched_barrier(0); /* pin load-issue cluster here */      \
    const ushort_t* pr = As + (PB)*4096;                                      \
    s16x8 af[4];                                                              \
    _Pragma("unroll") for (int rt = 0; rt < 4; ++rt)                          \
        af[rt] = *(const s16x8*)(pr + aros + rt * 128);                       \
    __builtin_amdgcn_s_setprio(1);                                            \
    MFMA8(af, BLC, 0)                                                         \
    MFMA8(af, bfHi, 4)                                                        \
    __builtin_amdgcn_s_setprio(0);                                            \
    __builtin_amdgcn_sched_barrier(0); /* keep bfHi reload below MFMAs */     \
    LOAD_BF4(bfHi, tn, 4)                                                     \
    PACK_WRITE_A(As + ((PB) ^ 1) * 4096)                                      \
    asm volatile("s_waitcnt lgkmcnt(0)" ::: "memory");                        \
    __builtin_amdgcn_s_barrier();                                             \
    __builtin_amdgcn_sched_barrier(0);                                        \
  }

  for (int tt = 0; tt < NC_; tt += 2) {
    ITER(0, bfA, bfB, tt)
    ITER(1, bfB, bfA, tt + 1)
  }
#undef ITER
#undef LOAD_HU
#undef PACK_WRITE_A
#undef LOAD_BF4
#undef MFMA8

  // epilogue: C/D layout col=lane&15, row=(lane>>4)*4+reg
  const int colg = lane & 15;
  const int rgrp = lane >> 4;
  float* ob = out + (((size_t)(b * L_ + l)) * S_ + ti + wr * 64) * S_ + wc * 128;
#pragma unroll
  for (int rt = 0; rt < 4; ++rt) {
    const int r0 = rt * 16 + rgrp * 4;
#pragma unroll
    for (int ct = 0; ct < 8; ++ct) {
      const int c = ct * 16 + colg;
      const float addc = T2[128 + wc * 128 + c] + bv;
      float* p = ob + (size_t)r0 * S_ + c;
#pragma unroll
      for (int r = 0; r < 4; ++r)
        p[(size_t)r * S_] = acc[rt][ct][r] + T2[wr * 64 + r0 + r] + addc;
    }
  }
}

extern "C" void kernel_launch(void* const* d_in, const int* in_sizes, int n_in,
                              void* d_out, int out_size, void* d_ws, size_t ws_size,
                              hipStream_t stream) {
  const float* head = (const float*)d_in[0];
  const float* dep = (const float*)d_in[1];
  const float* U = (const float*)d_in[2];
  const float* W = (const float*)d_in[3];
  const float* bias = (const float*)d_in[4];
  float* out = (float*)d_out;

  ushort_t* depb = (ushort_t*)d_ws;                              // 6,291,456 B
  float* t2h = (float*)((char*)d_ws + (size_t)B_ * S_ * D_ * 2);
  float* t2d = t2h + (size_t)B_ * L_ * S_;                       // 524,288 B each

  prep_kernel<<<512, 256, 0, stream>>>(head, dep, W, depb, t2h, t2d);
  main_kernel<<<B_ * L_ * 2, 256, 0, stream>>>(head, depb, U, bias, t2h, t2d, out);
}